// Round 1
// baseline (628.640 us; speedup 1.0000x reference)
//
#include <hip/hip_runtime.h>
#include <math.h>

#define F_IN 128
#define F_HID 16
#define F_OUT 8

// ---------------- degree / norm ----------------

__global__ void k_deg_init(float* __restrict__ deg, int n) {
    int i = blockIdx.x * blockDim.x + threadIdx.x;
    if (i < n) deg[i] = 1.0f;  // self-loop contribution
}

__global__ void k_deg_count(const int* __restrict__ dst, float* __restrict__ deg, int e) {
    int i = blockIdx.x * blockDim.x + threadIdx.x;
    if (i < e) atomicAdd(&deg[dst[i]], 1.0f);
}

__global__ void k_dinv(float* __restrict__ deg, int n) {
    int i = blockIdx.x * blockDim.x + threadIdx.x;
    if (i < n) deg[i] = rsqrtf(deg[i]);  // deg >= 1 always (self-loop)
}

// ---------------- layer 1: h1 = x @ W1 ----------------
// 256 threads = 16 rows x 16 cols. W1 (128x16=8KB) and x-tile (16x129 padded,
// ~8.25KB) staged in LDS. Padding 129 keeps the 4 distinct rows per wave in
// distinct banks.

__global__ __launch_bounds__(256) void k_gemm1(const float* __restrict__ x,
                                               const float* __restrict__ W1,
                                               float* __restrict__ h1, int n) {
    __shared__ float Ws[F_IN][F_HID];
    __shared__ float xs[16][F_IN + 1];
    int t = threadIdx.x;
    for (int i = t; i < F_IN * F_HID; i += 256) Ws[i / F_HID][i % F_HID] = W1[i];
    int row0 = blockIdx.x * 16;
    for (int i = t; i < 16 * F_IN; i += 256) {
        int r = i >> 7, c = i & 127;
        int gr = row0 + r;
        xs[r][c] = (gr < n) ? x[(long long)gr * F_IN + c] : 0.0f;
    }
    __syncthreads();
    int r = t >> 4, c = t & 15;
    float acc = 0.0f;
#pragma unroll
    for (int k = 0; k < F_IN; ++k) acc = fmaf(xs[r][k], Ws[k][c], acc);
    int gr = row0 + r;
    if (gr < n) h1[gr * F_HID + c] = acc;
}

// ---------------- layer 1: init out1 with self-loop + bias ----------------

__global__ void k_init1(const float* __restrict__ h1, const float* __restrict__ dinv,
                        const float* __restrict__ b1, float* __restrict__ out1, int n) {
    int gid = blockIdx.x * blockDim.x + threadIdx.x;
    if (gid < n * F_HID) {
        int i = gid >> 4, f = gid & 15;
        float di = dinv[i];
        out1[gid] = h1[gid] * di * di + b1[f];
    }
}

// ---------------- layer 1: edge scatter (16 lanes per edge) ----------------

__global__ void k_scatter1(const int* __restrict__ src, const int* __restrict__ dst,
                           const float* __restrict__ dinv, const float* __restrict__ h1,
                           float* __restrict__ out1, int e) {
    int gid = blockIdx.x * blockDim.x + threadIdx.x;
    if (gid < e * F_HID) {
        int ed = gid >> 4, f = gid & 15;
        int s = src[ed], d = dst[ed];
        float w = dinv[s] * dinv[d];
        atomicAdd(&out1[d * F_HID + f], h1[s * F_HID + f] * w);
    }
}

// ---------------- layer 2: relu + h2 = relu(out1) @ W2, init out2 ----------------

__global__ __launch_bounds__(256) void k_gemm2(const float* __restrict__ out1,
                                               const float* __restrict__ W2,
                                               const float* __restrict__ b2,
                                               const float* __restrict__ dinv,
                                               float* __restrict__ h2,
                                               float* __restrict__ out2, int n) {
    __shared__ float Ws[F_HID][F_OUT];
    int t = threadIdx.x;
    if (t < F_HID * F_OUT) Ws[t / F_OUT][t % F_OUT] = W2[t];
    __syncthreads();
    int i = blockIdx.x * blockDim.x + t;
    if (i >= n) return;
    const float4* p = (const float4*)(&out1[i * F_HID]);
    float r[F_HID];
#pragma unroll
    for (int q = 0; q < 4; ++q) {
        float4 v = p[q];
        r[q * 4 + 0] = fmaxf(v.x, 0.0f);
        r[q * 4 + 1] = fmaxf(v.y, 0.0f);
        r[q * 4 + 2] = fmaxf(v.z, 0.0f);
        r[q * 4 + 3] = fmaxf(v.w, 0.0f);
    }
    float di = dinv[i];
    float dd = di * di;
#pragma unroll
    for (int j = 0; j < F_OUT; ++j) {
        float acc = 0.0f;
#pragma unroll
        for (int k = 0; k < F_HID; ++k) acc = fmaf(r[k], Ws[k][j], acc);
        h2[i * F_OUT + j] = acc;
        out2[i * F_OUT + j] = acc * dd + b2[j];
    }
}

// ---------------- layer 2: edge scatter (8 lanes per edge) ----------------

__global__ void k_scatter2(const int* __restrict__ src, const int* __restrict__ dst,
                           const float* __restrict__ dinv, const float* __restrict__ h2,
                           float* __restrict__ out2, int e) {
    int gid = blockIdx.x * blockDim.x + threadIdx.x;
    if (gid < e * F_OUT) {
        int ed = gid >> 3, j = gid & 7;
        int s = src[ed], d = dst[ed];
        atomicAdd(&out2[d * F_OUT + j], h2[s * F_OUT + j] * dinv[s] * dinv[d]);
    }
}

// ---------------- log_softmax over 8 classes ----------------

__global__ void k_logsm(const float* __restrict__ out2, float* __restrict__ y, int n) {
    int i = blockIdx.x * blockDim.x + threadIdx.x;
    if (i >= n) return;
    const float4* p = (const float4*)(&out2[i * F_OUT]);
    float4 a = p[0], b = p[1];
    float v[8] = {a.x, a.y, a.z, a.w, b.x, b.y, b.z, b.w};
    float m = v[0];
#pragma unroll
    for (int j = 1; j < 8; ++j) m = fmaxf(m, v[j]);
    float s = 0.0f;
#pragma unroll
    for (int j = 0; j < 8; ++j) s += expf(v[j] - m);
    float lse = m + logf(s);
    float4 o0 = make_float4(v[0] - lse, v[1] - lse, v[2] - lse, v[3] - lse);
    float4 o1 = make_float4(v[4] - lse, v[5] - lse, v[6] - lse, v[7] - lse);
    float4* q = (float4*)(&y[i * F_OUT]);
    q[0] = o0;
    q[1] = o1;
}

// ---------------- launch ----------------

extern "C" void kernel_launch(void* const* d_in, const int* in_sizes, int n_in,
                              void* d_out, int out_size, void* d_ws, size_t ws_size,
                              hipStream_t stream) {
    const float* x  = (const float*)d_in[0];
    const int*   ei = (const int*)d_in[1];
    const float* W1 = (const float*)d_in[2];
    const float* b1 = (const float*)d_in[3];
    const float* W2 = (const float*)d_in[4];
    const float* b2 = (const float*)d_in[5];
    float* out = (float*)d_out;

    const int n = in_sizes[0] / F_IN;   // 100000
    const int e = in_sizes[1] / 2;      // 3200000
    const int* src = ei;
    const int* dst = ei + e;

    float* ws   = (float*)d_ws;
    float* dinv = ws;                     // n
    float* h1   = dinv + n;               // 16n
    float* out1 = h1 + (size_t)16 * n;    // 16n
    float* h2   = out1 + (size_t)16 * n;  // 8n
    float* out2 = h2 + (size_t)8 * n;     // 8n

    k_deg_init<<<(n + 255) / 256, 256, 0, stream>>>(dinv, n);
    k_deg_count<<<(e + 255) / 256, 256, 0, stream>>>(dst, dinv, e);
    k_dinv<<<(n + 255) / 256, 256, 0, stream>>>(dinv, n);
    k_gemm1<<<(n + 15) / 16, 256, 0, stream>>>(x, W1, h1, n);
    k_init1<<<(n * F_HID + 255) / 256, 256, 0, stream>>>(h1, dinv, b1, out1, n);
    {
        long long tot = (long long)e * F_HID;
        k_scatter1<<<(int)((tot + 255) / 256), 256, 0, stream>>>(src, dst, dinv, h1, out1, e);
    }
    k_gemm2<<<(n + 255) / 256, 256, 0, stream>>>(out1, W2, b2, dinv, h2, out2, n);
    {
        long long tot = (long long)e * F_OUT;
        k_scatter2<<<(int)((tot + 255) / 256), 256, 0, stream>>>(src, dst, dinv, h2, out2, e);
    }
    k_logsm<<<(n + 255) / 256, 256, 0, stream>>>(out2, out, n);
}

// Round 2
// 557.521 us; speedup vs baseline: 1.1276x; 1.1276x over previous
//
#include <hip/hip_runtime.h>
#include <math.h>

#define F_IN 128
#define F_HID 16
#define F_OUT 8

// ---------------- zero + degree ----------------

__global__ void k_zero(int* __restrict__ deg_i, int* __restrict__ cursor, int n) {
    int i = blockIdx.x * blockDim.x + threadIdx.x;
    if (i < n) { deg_i[i] = 0; cursor[i] = 0; }
}

__global__ void k_deg_count(const int* __restrict__ dst, int* __restrict__ deg_i, int e) {
    int i = blockIdx.x * blockDim.x + threadIdx.x;
    if (i < e) atomicAdd(&deg_i[dst[i]], 1);
}

__global__ void k_dinv(const int* __restrict__ deg_i, float* __restrict__ dinv, int n) {
    int i = blockIdx.x * blockDim.x + threadIdx.x;
    if (i < n) dinv[i] = rsqrtf((float)deg_i[i] + 1.0f);  // +1 = self-loop
}

// ---------------- exclusive scan of deg_i -> row_ptr (1024 elems/block) ----------------

__global__ __launch_bounds__(256) void k_scan1(const int* __restrict__ deg_i,
                                               int* __restrict__ row_ptr,
                                               int* __restrict__ bsum, int n) {
    __shared__ int sh[256];
    int t = threadIdx.x;
    int base = blockIdx.x * 1024 + t * 4;
    int v[4], s = 0;
#pragma unroll
    for (int q = 0; q < 4; ++q) {
        int idx = base + q;
        v[q] = (idx < n) ? deg_i[idx] : 0;
        s += v[q];
    }
    sh[t] = s;
    __syncthreads();
    for (int off = 1; off < 256; off <<= 1) {
        int x = (t >= off) ? sh[t - off] : 0;
        __syncthreads();
        sh[t] += x;
        __syncthreads();
    }
    int run = (t > 0) ? sh[t - 1] : 0;
#pragma unroll
    for (int q = 0; q < 4; ++q) {
        int idx = base + q;
        if (idx < n) row_ptr[idx] = run;
        run += v[q];
    }
    if (t == 255) bsum[blockIdx.x] = sh[255];
}

__global__ void k_scan2(int* __restrict__ bsum, int nb) {
    __shared__ int sh[128];
    int t = threadIdx.x;
    sh[t] = (t < nb) ? bsum[t] : 0;
    __syncthreads();
    for (int off = 1; off < 128; off <<= 1) {
        int x = (t >= off) ? sh[t - off] : 0;
        __syncthreads();
        sh[t] += x;
        __syncthreads();
    }
    if (t < nb) bsum[t] = (t > 0) ? sh[t - 1] : 0;
}

__global__ void k_scan3(int* __restrict__ row_ptr, const int* __restrict__ bsum, int n) {
    int i = blockIdx.x * blockDim.x + threadIdx.x;
    if (i < n) row_ptr[i] += bsum[i >> 10];
}

// ---------------- CSR slot assignment ----------------

__global__ void k_csr(const int* __restrict__ src, const int* __restrict__ dst,
                      const int* __restrict__ row_ptr, int* __restrict__ cursor,
                      int* __restrict__ csr_src, int e) {
    int i = blockIdx.x * blockDim.x + threadIdx.x;
    if (i < e) {
        int s = src[i], d = dst[i];
        int pos = row_ptr[d] + atomicAdd(&cursor[d], 1);
        csr_src[pos] = s;
    }
}

// ---------------- layer 1 GEMM: g1 = dinv * (x @ W1) ----------------

__global__ __launch_bounds__(256) void k_gemm1(const float* __restrict__ x,
                                               const float* __restrict__ W1,
                                               const float* __restrict__ dinv,
                                               float* __restrict__ g1, int n) {
    __shared__ float Ws[F_IN][F_HID];
    __shared__ float xs[16][F_IN + 1];
    int t = threadIdx.x;
    for (int i = t; i < F_IN * F_HID; i += 256) Ws[i / F_HID][i % F_HID] = W1[i];
    int row0 = blockIdx.x * 16;
    for (int i = t; i < 16 * F_IN; i += 256) {
        int r = i >> 7, c = i & 127;
        int gr = row0 + r;
        xs[r][c] = (gr < n) ? x[(long long)gr * F_IN + c] : 0.0f;
    }
    __syncthreads();
    int r = t >> 4, c = t & 15;
    float acc = 0.0f;
#pragma unroll
    for (int k = 0; k < F_IN; ++k) acc = fmaf(xs[r][k], Ws[k][c], acc);
    int gr = row0 + r;
    if (gr < n) g1[gr * F_HID + c] = acc * dinv[gr];
}

// ---------------- layer 1 gather: out1 = relu(dinv[d]*(sum g1[src] + g1[d]) + b1) ----------------
// 16 lanes per node; csr index broadcast within the lane group, g1 row read = 64B coalesced.

__global__ __launch_bounds__(256) void k_gather1(const int* __restrict__ row_ptr,
                                                 const int* __restrict__ deg_i,
                                                 const int* __restrict__ csr_src,
                                                 const float* __restrict__ dinv,
                                                 const float* __restrict__ g1,
                                                 const float* __restrict__ b1,
                                                 float* __restrict__ out1, int n) {
    int d = blockIdx.x * 16 + (threadIdx.x >> 4);
    int f = threadIdx.x & 15;
    if (d >= n) return;
    int st = row_ptr[d], cnt = deg_i[d];
    float acc = g1[d * F_HID + f];  // self-loop
    int k = 0;
    for (; k + 4 <= cnt; k += 4) {
        int s0 = csr_src[st + k], s1 = csr_src[st + k + 1];
        int s2 = csr_src[st + k + 2], s3 = csr_src[st + k + 3];
        acc += g1[s0 * F_HID + f];
        acc += g1[s1 * F_HID + f];
        acc += g1[s2 * F_HID + f];
        acc += g1[s3 * F_HID + f];
    }
    for (; k < cnt; ++k) acc += g1[csr_src[st + k] * F_HID + f];
    out1[d * F_HID + f] = fmaxf(dinv[d] * acc + b1[f], 0.0f);
}

// ---------------- layer 2 GEMM: g2 = dinv * (out1 @ W2) ----------------

__global__ __launch_bounds__(256) void k_gemm2(const float* __restrict__ out1,
                                               const float* __restrict__ W2,
                                               const float* __restrict__ dinv,
                                               float* __restrict__ g2, int n) {
    __shared__ float Ws[F_HID][F_OUT];
    int t = threadIdx.x;
    if (t < F_HID * F_OUT) Ws[t / F_OUT][t % F_OUT] = W2[t];
    __syncthreads();
    int i = blockIdx.x * blockDim.x + t;
    if (i >= n) return;
    const float4* p = (const float4*)(&out1[i * F_HID]);
    float r[F_HID];
#pragma unroll
    for (int q = 0; q < 4; ++q) {
        float4 v = p[q];
        r[q * 4 + 0] = v.x; r[q * 4 + 1] = v.y; r[q * 4 + 2] = v.z; r[q * 4 + 3] = v.w;
    }
    float di = dinv[i];
    float o[F_OUT];
#pragma unroll
    for (int j = 0; j < F_OUT; ++j) {
        float acc = 0.0f;
#pragma unroll
        for (int kk = 0; kk < F_HID; ++kk) acc = fmaf(r[kk], Ws[kk][j], acc);
        o[j] = acc * di;
    }
    float4* q4 = (float4*)(&g2[i * F_OUT]);
    q4[0] = make_float4(o[0], o[1], o[2], o[3]);
    q4[1] = make_float4(o[4], o[5], o[6], o[7]);
}

// ---------------- layer 2 gather + bias + log_softmax ----------------
// 8 lanes per node; cross-feature reduce via shfl_xor within the 8-lane group.

__global__ __launch_bounds__(256) void k_gather2(const int* __restrict__ row_ptr,
                                                 const int* __restrict__ deg_i,
                                                 const int* __restrict__ csr_src,
                                                 const float* __restrict__ dinv,
                                                 const float* __restrict__ g2,
                                                 const float* __restrict__ b2,
                                                 float* __restrict__ out, int n) {
    int d = blockIdx.x * 32 + (threadIdx.x >> 3);
    int j = threadIdx.x & 7;
    if (d >= n) return;
    int st = row_ptr[d], cnt = deg_i[d];
    float acc = g2[d * F_OUT + j];  // self-loop
    int k = 0;
    for (; k + 4 <= cnt; k += 4) {
        int s0 = csr_src[st + k], s1 = csr_src[st + k + 1];
        int s2 = csr_src[st + k + 2], s3 = csr_src[st + k + 3];
        acc += g2[s0 * F_OUT + j];
        acc += g2[s1 * F_OUT + j];
        acc += g2[s2 * F_OUT + j];
        acc += g2[s3 * F_OUT + j];
    }
    for (; k < cnt; ++k) acc += g2[csr_src[st + k] * F_OUT + j];
    float v = dinv[d] * acc + b2[j];
    // log_softmax across the 8 lanes of this group
    float m = v;
    m = fmaxf(m, __shfl_xor(m, 1));
    m = fmaxf(m, __shfl_xor(m, 2));
    m = fmaxf(m, __shfl_xor(m, 4));
    float ex = expf(v - m);
    float ssum = ex;
    ssum += __shfl_xor(ssum, 1);
    ssum += __shfl_xor(ssum, 2);
    ssum += __shfl_xor(ssum, 4);
    out[d * F_OUT + j] = v - m - logf(ssum);
}

// ---------------- launch ----------------

extern "C" void kernel_launch(void* const* d_in, const int* in_sizes, int n_in,
                              void* d_out, int out_size, void* d_ws, size_t ws_size,
                              hipStream_t stream) {
    const float* x  = (const float*)d_in[0];
    const int*   ei = (const int*)d_in[1];
    const float* W1 = (const float*)d_in[2];
    const float* b1 = (const float*)d_in[3];
    const float* W2 = (const float*)d_in[4];
    const float* b2 = (const float*)d_in[5];
    float* out = (float*)d_out;

    const int n = in_sizes[0] / F_IN;   // 100000
    const int e = in_sizes[1] / 2;      // 3200000
    const int* src = ei;
    const int* dst = ei + e;

    char* w = (char*)d_ws;
    float* dinv   = (float*)w; w += (size_t)n * 4;
    int* deg_i    = (int*)w;   w += (size_t)n * 4;
    int* row_ptr  = (int*)w;   w += (size_t)n * 4;
    int* cursor   = (int*)w;   w += (size_t)n * 4;
    int* bsum     = (int*)w;   w += 1024;
    int* csr_src  = (int*)w;   w += (size_t)e * 4;
    float* g1     = (float*)w; w += (size_t)n * F_HID * 4;
    float* out1   = (float*)w; w += (size_t)n * F_HID * 4;
    float* g2     = (float*)w; w += (size_t)n * F_OUT * 4;

    int nb = (n + 1023) / 1024;  // 98 blocks, fits k_scan2's 128-wide scan

    k_zero<<<(n + 255) / 256, 256, 0, stream>>>(deg_i, cursor, n);
    k_deg_count<<<(e + 255) / 256, 256, 0, stream>>>(dst, deg_i, e);
    k_dinv<<<(n + 255) / 256, 256, 0, stream>>>(deg_i, dinv, n);
    k_scan1<<<nb, 256, 0, stream>>>(deg_i, row_ptr, bsum, n);
    k_scan2<<<1, 128, 0, stream>>>(bsum, nb);
    k_scan3<<<(n + 255) / 256, 256, 0, stream>>>(row_ptr, bsum, n);
    k_csr<<<(e + 255) / 256, 256, 0, stream>>>(src, dst, row_ptr, cursor, csr_src, e);
    k_gemm1<<<(n + 15) / 16, 256, 0, stream>>>(x, W1, dinv, g1, n);
    k_gather1<<<(n + 15) / 16, 256, 0, stream>>>(row_ptr, deg_i, csr_src, dinv, g1, b1, out1, n);
    k_gemm2<<<(n + 255) / 256, 256, 0, stream>>>(out1, W2, dinv, g2, n);
    k_gather2<<<(n + 31) / 32, 256, 0, stream>>>(row_ptr, deg_i, csr_src, dinv, g2, b2, out, n);
}